// Round 7
// baseline (730.206 us; speedup 1.0000x reference)
//
#include <hip/hip_runtime.h>

// GraphSAGE round 15: scatter rebuilt as direct global-atomic scatter
// (r14 counters: 48 us at 11% occupancy / 1.3% VALU / 4.6% HBM — the 2-phase
// LDS-histogram design was latency-starved at 98 blocks). Grid-stride int4,
// 4 independent atomic chains per thread. bcur stays relative-fill.
// Everything else identical to r14 (391.5 us).

#define F   128
#define FH  64
#define EPS 1e-5f
#define CAP 4096            // slots per bucket (avg fill 2046)

typedef __attribute__((ext_vector_type(8))) short short8v;
typedef __attribute__((ext_vector_type(4))) short short4v;
typedef __attribute__((ext_vector_type(4))) float floatx4;
typedef __attribute__((ext_vector_type(2))) float floatx2;
typedef __attribute__((ext_vector_type(4))) unsigned int uint4v;

__device__ inline unsigned short f2bf(float f) {
    unsigned u = __builtin_bit_cast(unsigned, f);
    u += 0x7fff + ((u >> 16) & 1);          // round-to-nearest-even
    return (unsigned short)(u >> 16);
}
__device__ inline float bflo(unsigned u) { return __builtin_bit_cast(float, u << 16); }
__device__ inline float bfhi(unsigned u) { return __builtin_bit_cast(float, u & 0xffff0000u); }

// async global->LDS, 16B per lane; LDS dest wave-uniform base + lane*16,
// global src per-lane (frag-order permutation is applied on the global side)
__device__ inline void gl_lds16(const void* g, void* l) {
    __builtin_amdgcn_global_load_lds(
        (const __attribute__((address_space(1))) void*)g,
        (__attribute__((address_space(3))) void*)l, 16, 0, 0);
}

#define PIN8(v) asm volatile("" : "+v"(v))

// ---------------- x -> bf16 + fp8 ----------------
__global__ __launch_bounds__(256) void conv_dual_kernel(
    const float* __restrict__ x, unsigned short* __restrict__ xb,
    unsigned* __restrict__ x8, int total4)
{
    int t = blockIdx.x * 256 + threadIdx.x;
    if (t >= total4) return;
    float4 v = reinterpret_cast<const float4*>(x)[t];
    short4v p = { (short)f2bf(v.x), (short)f2bf(v.y), (short)f2bf(v.z), (short)f2bf(v.w) };
    *reinterpret_cast<short4v*>(xb + t * 4) = p;
    unsigned p8 = __builtin_amdgcn_cvt_pk_fp8_f32(v.x, v.y, 0, false);
    p8 = __builtin_amdgcn_cvt_pk_fp8_f32(v.z, v.w, p8, true);
    x8[t] = p8;
}

// ---------------- CSR build: direct global-atomic scatter ----------------
// 4 edges per thread (int4 loads), 4 independent atomic+store chains.
__global__ __launch_bounds__(256) void scatter_direct_kernel(
    const int* __restrict__ src, const int* __restrict__ dst,
    int* __restrict__ bcur, int* __restrict__ keys, int E)
{
    int t = blockIdx.x * 256 + threadIdx.x;
    int e0 = t * 4;
    if (e0 + 3 < E) {
        int4 d4 = *reinterpret_cast<const int4*>(dst + e0);
        int4 s4 = *reinterpret_cast<const int4*>(src + e0);
        int b0 = d4.x >> 7, b1 = d4.y >> 7, b2 = d4.z >> 7, b3 = d4.w >> 7;
        int p0 = atomicAdd(&bcur[b0], 1);
        int p1 = atomicAdd(&bcur[b1], 1);
        int p2 = atomicAdd(&bcur[b2], 1);
        int p3 = atomicAdd(&bcur[b3], 1);
        if (p0 < CAP) keys[b0 * CAP + p0] = (s4.x << 7) | (d4.x & 127);
        if (p1 < CAP) keys[b1 * CAP + p1] = (s4.y << 7) | (d4.y & 127);
        if (p2 < CAP) keys[b2 * CAP + p2] = (s4.z << 7) | (d4.z & 127);
        if (p3 < CAP) keys[b3 * CAP + p3] = (s4.w << 7) | (d4.w & 127);
    } else {
        for (int e = e0; e < E; ++e) {
            int d = dst[e], s = src[e];
            int b = d >> 7;
            int p = atomicAdd(&bcur[b], 1);
            if (p < CAP) keys[b * CAP + p] = (s << 7) | (d & 127);
        }
    }
}

__global__ __launch_bounds__(256) void bucket_sort_kernel(
    const int* __restrict__ keys, const int* __restrict__ bcur,
    int* __restrict__ eid, int* __restrict__ start, int* __restrict__ deg, int n)
{
    __shared__ int cnt[128], cur[128], sc[128];
    __shared__ int sorted[CAP];
    const int b = blockIdx.x;
    const int tid = threadIdx.x;
    const int base = b * CAP;
    int count = bcur[b];                 // relative fill
    if (count > CAP) count = CAP;
    const int v0 = b << 7;

    if (tid < 128) cnt[tid] = 0;
    __syncthreads();
    for (int i = tid; i < count; i += 256)
        atomicAdd(&cnt[keys[base + i] & 127], 1);
    __syncthreads();
    if (tid < 128) sc[tid] = cnt[tid];
    __syncthreads();
    for (int o = 1; o < 128; o <<= 1) {
        int a = (tid < 128 && tid >= o) ? sc[tid - o] : 0;
        __syncthreads();
        if (tid < 128) sc[tid] += a;
        __syncthreads();
    }
    if (tid < 128) {
        int excl = sc[tid] - cnt[tid];
        int v = v0 + tid;
        if (v < n) { start[v] = base + excl; deg[v] = cnt[tid]; }
        cur[tid] = excl;
    }
    __syncthreads();
    for (int i = tid; i < count; i += 256) {
        int k = keys[base + i];
        int p = atomicAdd(&cur[k & 127], 1);
        sorted[p] = k >> 7;
    }
    __syncthreads();
    for (int i = tid; i < count; i += 256) eid[base + i] = sorted[i];
}

// ---------------- gather aggregation (fp8 rows): agg[v] = mean x[N(v)] ------------
// v3: 8-edge unroll -> 4 gather loads in flight per lane; floatx2 pk adds.
// lanes 0-31 = even edges, 32-63 = odd edges; lane accumulates feats 4q..4q+3.
__global__ __launch_bounds__(256) void aggregate_kernel(
    const unsigned* __restrict__ x8w, const int* __restrict__ eid,
    const int* __restrict__ start, const int* __restrict__ deg,
    unsigned int* __restrict__ aggb2, int n)
{
    int w = (blockIdx.x * 256 + threadIdx.x) >> 6;
    int l = threadIdx.x & 63;
    if (w >= n) return;
    const int beg  = start[w];
    const int c    = deg[w];
    const int half = l >> 5;
    const int q    = l & 31;
    floatx2 acc01 = {0.f, 0.f};
    floatx2 acc23 = {0.f, 0.f};
    int off = beg, rem = c;
    while (rem > 0) {
        int m = rem < 64 ? rem : 64;
        int id = (l < m) ? eid[off + l] : 0;
        int j = 0;
        for (; j + 7 < m; j += 8) {                 // 8 edges: 4 per half
            int sA = __shfl(id, j + half);
            int sB = __shfl(id, j + 2 + half);
            int sC = __shfl(id, j + 4 + half);
            int sD = __shfl(id, j + 6 + half);
            unsigned dA = x8w[(size_t)sA * 32 + q];
            unsigned dB = x8w[(size_t)sB * 32 + q];
            unsigned dC = x8w[(size_t)sC * 32 + q];
            unsigned dD = x8w[(size_t)sD * 32 + q];
            acc01 += __builtin_amdgcn_cvt_pk_f32_fp8((int)dA, false);
            acc23 += __builtin_amdgcn_cvt_pk_f32_fp8((int)dA, true);
            acc01 += __builtin_amdgcn_cvt_pk_f32_fp8((int)dB, false);
            acc23 += __builtin_amdgcn_cvt_pk_f32_fp8((int)dB, true);
            acc01 += __builtin_amdgcn_cvt_pk_f32_fp8((int)dC, false);
            acc23 += __builtin_amdgcn_cvt_pk_f32_fp8((int)dC, true);
            acc01 += __builtin_amdgcn_cvt_pk_f32_fp8((int)dD, false);
            acc23 += __builtin_amdgcn_cvt_pk_f32_fp8((int)dD, true);
        }
        for (; j + 1 < m; j += 2) {                 // 2 edges: 1 per half
            int sA = __shfl(id, j + half);
            unsigned dA = x8w[(size_t)sA * 32 + q];
            acc01 += __builtin_amdgcn_cvt_pk_f32_fp8((int)dA, false);
            acc23 += __builtin_amdgcn_cvt_pk_f32_fp8((int)dA, true);
        }
        if (j < m) {                                // single leftover edge
            int sA = __shfl(id, j);                 // shfl while converged
            if (half == 0) {
                unsigned dA = x8w[(size_t)sA * 32 + q];
                acc01 += __builtin_amdgcn_cvt_pk_f32_fp8((int)dA, false);
                acc23 += __builtin_amdgcn_cvt_pk_f32_fp8((int)dA, true);
            }
        }
        off += m; rem -= m;
    }
    float a0 = acc01.x, a1 = acc01.y, a2 = acc23.x, a3 = acc23.y;
    a0 += __shfl_xor(a0, 32);
    a1 += __shfl_xor(a1, 32);
    a2 += __shfl_xor(a2, 32);
    a3 += __shfl_xor(a3, 32);
    if (half == 0) {
        float inv = 1.0f / fmaxf((float)c, 1.0f);
        uint2 p;
        p.x = (unsigned)f2bf(a0 * inv) | ((unsigned)f2bf(a1 * inv) << 16);
        p.y = (unsigned)f2bf(a2 * inv) | ((unsigned)f2bf(a3 * inv) << 16);
        *reinterpret_cast<uint2*>(aggb2 + (size_t)w * 64 + 2 * q) = p;
    }
}

// ---------------- weight prep: fp32 [K][N] -> bf16 fragment order ----------------
struct PrepArgs { const float* s[8]; unsigned short* d[8]; };

__global__ __launch_bounds__(256) void prep_all_kernel(PrepArgs a)
{
    int t = blockIdx.x * 256 + threadIdx.x;
    int m, idx, K, N;
    if (t < 4 * 16384)            { m = t >> 14;                 idx = t & 16383; K = 128; N = 128; }
    else if (t < 4 * 16384 + 2 * 8192) { int u = t - 4 * 16384;  m = 4 + (u >> 13); idx = u & 8191; K = 128; N = 64; }
    else                          { int u = t - 4 * 16384 - 2 * 8192; if (u >= 2 * 8192) return;
                                    m = 6 + (u >> 13); idx = u & 8191; K = 64; N = 128; }
    int k = idx / N, c = idx % N;
    int ct = c >> 4, ks = k >> 5;
    int lane = (c & 15) + (((k & 31) >> 3) << 4);
    int j = k & 7;
    a.d[m][((ct * (K >> 5) + ks) * 64 + lane) * 8 + j] = f2bf(a.s[m][idx]);
}

// ---------------- fused MFMA GEMM: pinned weights, async staging, 2 tiles ----------
__global__ __launch_bounds__(256, 3) void fused_gemm_mfma(
    const unsigned short* __restrict__ xb, const unsigned short* __restrict__ aggb,
    const unsigned short* __restrict__ wlf, const unsigned short* __restrict__ wrf,
    const unsigned short* __restrict__ whf, const unsigned short* __restrict__ wsf,
    const float* __restrict__ bl, const float* __restrict__ sb1,
    const float* __restrict__ sb2,
    uint4v* __restrict__ ypk4, uint4v* __restrict__ spk4,
    float* __restrict__ colsum, float* __restrict__ colsq, int n, int ntiles)
{
    __shared__ unsigned short xsf[16 * 64 * 8];   // 16 KB: x frags
    __shared__ unsigned short abuf[16 * 64 * 8];  // 16 KB: agg frags
    __shared__ unsigned short hbuf[64 * 88];      // 11 KB: relu(h)

    const int tid = threadIdx.x;
    const int w = tid >> 6;
    const int l = tid & 63;

    // ---- register-resident B fragments, loaded ONCE, pinned ----
    const short8v* wl8 = (const short8v*)wlf;
    const short8v* wr8 = (const short8v*)wrf;
    const short8v* wh8 = (const short8v*)whf;
    const short8v* ws8 = (const short8v*)wsf;
    short8v bWl[2][4], bWr[2][4];
#pragma unroll
    for (int ct = 0; ct < 2; ++ct)
#pragma unroll
        for (int ks = 0; ks < 4; ++ks) {
            int idx = ((w * 2 + ct) * 4 + ks) * 64 + l;
            bWl[ct][ks] = wl8[idx];
            bWr[ct][ks] = wr8[idx];
        }
    short8v bh[4];
#pragma unroll
    for (int ks = 0; ks < 4; ++ks) bh[ks] = wh8[(w * 4 + ks) * 64 + l];
    short8v bs[2][2];
#pragma unroll
    for (int ct = 0; ct < 2; ++ct)
#pragma unroll
        for (int ks = 0; ks < 2; ++ks)
            bs[ct][ks] = ws8[((w * 2 + ct) * 2 + ks) * 64 + l];
#pragma unroll
    for (int ct = 0; ct < 2; ++ct)
#pragma unroll
        for (int ks = 0; ks < 4; ++ks) { PIN8(bWl[ct][ks]); PIN8(bWr[ct][ks]); }
#pragma unroll
    for (int ks = 0; ks < 4; ++ks) PIN8(bh[ks]);
#pragma unroll
    for (int ct = 0; ct < 2; ++ct)
#pragma unroll
        for (int ks = 0; ks < 2; ++ks) PIN8(bs[ct][ks]);

    const int col0 = w * 32 + (l & 15);
    const float bias0 = bl[col0], bias1 = bl[col0 + 16];
    const int hcol = w * 16 + (l & 15);
    const float hbias = sb1[hcol];
    const float sbias0 = sb2[col0], sbias1 = sb2[col0 + 16];

    const short8v* xs8 = (const short8v*)xsf;
    const short8v* as8 = (const short8v*)abuf;
    const int r15 = l & 15;
    const int s23 = l >> 4;

    float psum0 = 0.f, psq0 = 0.f, psum1 = 0.f, psq1 = 0.f;

    for (int ti = 0; ti < 2; ++ti) {
        const int t = blockIdx.x * 2 + ti;
        if (t >= ntiles) break;
        const int r0 = t * 64;
        const size_t pbase = (size_t)t * 1024;

        // ---- async staging: linear LDS dest, frag-order global permutation ----
#pragma unroll
        for (int c = 0; c < 4; ++c) {
            int u = w * 4 + c;                      // region 0..15
            int rt = u >> 2, ks = u & 3;
            int row = r0 + rt * 16 + r15;
            if (row >= n) row = n - 1;
            size_t goff = (size_t)row * F + (size_t)(ks * 4 + s23) * 8;   // shorts
            gl_lds16(xb + goff,   &xsf[u * 512]);
            gl_lds16(aggb + goff, &abuf[u * 512]);
        }
        __syncthreads();   // staging complete (vmcnt drained)

        // ---- phase Y+H: MFMAs; packed y store + stats; h straight to hbuf ----
#pragma unroll
        for (int rt = 0; rt < 4; ++rt) {
            floatx4 acc0 = {0.f, 0.f, 0.f, 0.f};
            floatx4 acc1 = {0.f, 0.f, 0.f, 0.f};
            floatx4 hacc = {0.f, 0.f, 0.f, 0.f};
#pragma unroll
            for (int ks = 0; ks < 4; ++ks) {
                short8v ax = xs8[(rt * 4 + ks) * 64 + l];
                short8v aa = as8[(rt * 4 + ks) * 64 + l];
                acc0 = __builtin_amdgcn_mfma_f32_16x16x32_bf16(aa, bWl[0][ks], acc0, 0, 0, 0);
                acc0 = __builtin_amdgcn_mfma_f32_16x16x32_bf16(ax, bWr[0][ks], acc0, 0, 0, 0);
                acc1 = __builtin_amdgcn_mfma_f32_16x16x32_bf16(aa, bWl[1][ks], acc1, 0, 0, 0);
                acc1 = __builtin_amdgcn_mfma_f32_16x16x32_bf16(ax, bWr[1][ks], acc1, 0, 0, 0);
                hacc = __builtin_amdgcn_mfma_f32_16x16x32_bf16(ax, bh[ks], hacc, 0, 0, 0);
            }
            int rowb = r0 + rt * 16 + (l >> 4) * 4;
            int hrowb = rt * 16 + (l >> 4) * 4;
            uint4v yq;
#pragma unroll
            for (int reg = 0; reg < 4; ++reg) {
                float v0 = acc0[reg] + bias0;
                float v1 = acc1[reg] + bias1;
                yq[reg] = (unsigned)f2bf(v0) | ((unsigned)f2bf(v1) << 16);
                if (rowb + reg < n) {
                    psum0 += v0; psq0 += v0 * v0;
                    psum1 += v1; psq1 += v1 * v1;
                }
                hbuf[(hrowb + reg) * 88 + hcol] = f2bf(fmaxf(hacc[reg] + hbias, 0.f));
            }
            ypk4[pbase + rt * 256 + tid] = yq;       // 1 KB/wave contiguous
        }
        __syncthreads();   // h visible; all frag reads retired

        // ---- phase S MFMAs (reads hbuf); packed skip store ----
#pragma unroll
        for (int rt = 0; rt < 4; ++rt) {
            floatx4 s0 = {0.f, 0.f, 0.f, 0.f};
            floatx4 s1 = {0.f, 0.f, 0.f, 0.f};
#pragma unroll
            for (int ks = 0; ks < 2; ++ks) {
                short8v ah = *(const short8v*)&hbuf[(rt * 16 + (l & 15)) * 88 + ks * 32 + (l >> 4) * 8];
                s0 = __builtin_amdgcn_mfma_f32_16x16x32_bf16(ah, bs[0][ks], s0, 0, 0, 0);
                s1 = __builtin_amdgcn_mfma_f32_16x16x32_bf16(ah, bs[1][ks], s1, 0, 0, 0);
            }
            uint4v sq;
#pragma unroll
            for (int reg = 0; reg < 4; ++reg)
                sq[reg] = (unsigned)f2bf(s0[reg] + sbias0) |
                          ((unsigned)f2bf(s1[reg] + sbias1) << 16);
            spk4[pbase + rt * 256 + tid] = sq;
        }
        // next tile's staging follows its own barrier -> race-free
    }

    // ---- BN partial stats: one atomic set per block (both tiles) ----
    psum0 += __shfl_xor(psum0, 16); psum0 += __shfl_xor(psum0, 32);
    psq0  += __shfl_xor(psq0, 16);  psq0  += __shfl_xor(psq0, 32);
    psum1 += __shfl_xor(psum1, 16); psum1 += __shfl_xor(psum1, 32);
    psq1  += __shfl_xor(psq1, 16);  psq1  += __shfl_xor(psq1, 32);
    if (l < 16) {
        unsafeAtomicAdd(&colsum[col0], psum0);
        unsafeAtomicAdd(&colsq[col0], psq0);
        unsafeAtomicAdd(&colsum[col0 + 16], psum1);
        unsafeAtomicAdd(&colsq[col0 + 16], psq1);
    }
}

// ---------------- apply: packed reads, inline BN finalize, direct stores ----------
__global__ __launch_bounds__(256) void apply_packed_kernel(
    const uint4v* __restrict__ ypk4, const uint4v* __restrict__ spk4,
    const float* __restrict__ csum, const float* __restrict__ csq,
    const float* __restrict__ g, const float* __restrict__ beta,
    unsigned short* __restrict__ out_bf, unsigned char* __restrict__ out_f8,
    float* __restrict__ out_f32, int out_fp32, float invn, int n)
{
    const int tid = threadIdx.x;
    const int w = tid >> 6, l = tid & 63;
    const int col0 = w * 32 + (l & 15);
    const int r0 = blockIdx.x * 64;
    const size_t pbase = (size_t)blockIdx.x * 1024;

    const float mu0 = csum[col0] * invn;
    const float mu1 = csum[col0 + 16] * invn;
    const float sc0 = rsqrtf(csq[col0] * invn - mu0 * mu0 + EPS) * g[col0];
    const float sc1 = rsqrtf(csq[col0 + 16] * invn - mu1 * mu1 + EPS) * g[col0 + 16];
    const float sh0 = beta[col0] - mu0 * sc0;
    const float sh1 = beta[col0 + 16] - mu1 * sc1;

#pragma unroll
    for (int rt = 0; rt < 4; ++rt) {
        uint4v yv = ypk4[pbase + rt * 256 + tid];
        uint4v sv = spk4[pbase + rt * 256 + tid];
        int rowb = r0 + rt * 16 + (l >> 4) * 4;
#pragma unroll
        for (int reg = 0; reg < 4; ++reg) {
            int row = rowb + reg;
            if (row >= n) continue;
            float o0 = fmaxf(bflo(yv[reg]) * sc0 + sh0 + bflo(sv[reg]), 0.f);
            float o1 = fmaxf(bfhi(yv[reg]) * sc1 + sh1 + bfhi(sv[reg]), 0.f);
            if (out_fp32) {
                out_f32[(size_t)row * F + col0]      = o0;
                out_f32[(size_t)row * F + col0 + 16] = o1;
            } else {
                out_bf[(size_t)row * F + col0]      = f2bf(o0);
                out_bf[(size_t)row * F + col0 + 16] = f2bf(o1);
                unsigned pk = __builtin_amdgcn_cvt_pk_fp8_f32(o0, o1, 0, false);
                out_f8[(size_t)row * F + col0]      = (unsigned char)(pk & 0xff);
                out_f8[(size_t)row * F + col0 + 16] = (unsigned char)((pk >> 8) & 0xff);
            }
        }
    }
}

extern "C" void kernel_launch(void* const* d_in, const int* in_sizes, int n_in,
                              void* d_out, int out_size, void* d_ws, size_t ws_size,
                              hipStream_t stream)
{
    const float* x    = (const float*)d_in[0];
    const int*   ei   = (const int*)d_in[1];
    const float* Wl1  = (const float*)d_in[2];
    const float* bl1  = (const float*)d_in[3];
    const float* Wr1  = (const float*)d_in[4];
    const float* Wl2  = (const float*)d_in[5];
    const float* bl2  = (const float*)d_in[6];
    const float* Wr2  = (const float*)d_in[7];
    const float* s1w1 = (const float*)d_in[8];
    const float* s1b1 = (const float*)d_in[9];
    const float* s1w2 = (const float*)d_in[10];
    const float* s1b2 = (const float*)d_in[11];
    const float* s2w1 = (const float*)d_in[12];
    const float* s2b1 = (const float*)d_in[13];
    const float* s2w2 = (const float*)d_in[14];
    const float* s2b2 = (const float*)d_in[15];
    const float* g1   = (const float*)d_in[16];
    const float* be1  = (const float*)d_in[17];
    const float* g2   = (const float*)d_in[18];
    const float* be2  = (const float*)d_in[19];

    const int n = in_sizes[0] / F;       // 100000
    const int E = in_sizes[1] / 2;       // 1600000
    const int* src = ei;
    const int* dst = ei + E;
    const int B = (n + 127) >> 7;        // 782 buckets
    const int ntiles = (n + 63) >> 6;    // 1563
    const int gblocks = (ntiles + 1) >> 1; // 782, 2 tiles/block

    // ---- workspace carve-up (float units) ----
    float* ws = (float*)d_ws;
    size_t off = 0;
    float* csum1 = ws + off; off += F;
    float* csq1  = ws + off; off += F;
    float* csum2 = ws + off; off += F;
    float* csq2  = ws + off; off += F;
    int* bcur = (int*)(ws + off); off += 1024;
    unsigned short* xb    = (unsigned short*)(ws + off); off += (size_t)n * F / 2;
    unsigned short* x1b   = (unsigned short*)(ws + off); off += (size_t)n * F / 2;
    unsigned* ypkbuf = (unsigned*)(ws + off); off += (size_t)ntiles * 4096;   // packed y
    unsigned* spkbuf = (unsigned*)(ws + off); off += (size_t)ntiles * 4096;   // packed skip
    unsigned short* aggb  = (unsigned short*)(ws + off); off += (size_t)n * F / 2;
    unsigned* x8  = (unsigned*)(ws + off); off += (size_t)n * F / 4;   // fp8 rows
    unsigned* x18 = (unsigned*)(ws + off); off += (size_t)n * F / 4;
    unsigned short* wbf   = (unsigned short*)(ws + off);
    size_t woff = 0;
    unsigned short* fWl1  = wbf + woff; woff += F * F;
    unsigned short* fWr1  = wbf + woff; woff += F * F;
    unsigned short* fWl2  = wbf + woff; woff += F * F;
    unsigned short* fWr2  = wbf + woff; woff += F * F;
    unsigned short* fs1w1 = wbf + woff; woff += F * FH;
    unsigned short* fs2w1 = wbf + woff; woff += F * FH;
    unsigned short* fs1w2 = wbf + woff; woff += FH * F;
    unsigned short* fs2w2 = wbf + woff; woff += FH * F;
    off += (woff + 1) / 2;
    int* iws = (int*)(ws + off);
    size_t ioff = 0;
    int* start = iws + ioff; ioff += n;
    int* deg   = iws + ioff; ioff += n;
    int* keys  = iws + ioff; ioff += (size_t)B * CAP;
    int* eid   = iws + ioff; ioff += (size_t)B * CAP;

    const int total4 = n * (F / 4);
    const int ablocks = (n + 3) / 4;
    const float invn = 1.0f / (float)n;

    // ---- single startup memset: stats (2 KB) + bcur (4 KB) ----
    hipMemsetAsync(ws, 0, 512 * sizeof(float) + 1024 * sizeof(int), stream);

    // ---- x -> bf16 + fp8 ----
    conv_dual_kernel<<<(total4 + 255) / 256, 256, 0, stream>>>(x, xb, x8, total4);

    // ---- CSR build ----
    scatter_direct_kernel<<<((E + 3) / 4 + 255) / 256, 256, 0, stream>>>(
        src, dst, bcur, keys, E);
    bucket_sort_kernel<<<B, 256, 0, stream>>>(keys, bcur, eid, start, deg, n);

    // ---- weight prep ----
    PrepArgs pa;
    pa.s[0] = Wl1;  pa.d[0] = fWl1;
    pa.s[1] = Wr1;  pa.d[1] = fWr1;
    pa.s[2] = Wl2;  pa.d[2] = fWl2;
    pa.s[3] = Wr2;  pa.d[3] = fWr2;
    pa.s[4] = s1w1; pa.d[4] = fs1w1;
    pa.s[5] = s2w1; pa.d[5] = fs2w1;
    pa.s[6] = s1w2; pa.d[6] = fs1w2;
    pa.s[7] = s2w2; pa.d[7] = fs2w2;
    prep_all_kernel<<<384, 256, 0, stream>>>(pa);

    // ---- layer 1 ----
    aggregate_kernel<<<ablocks, 256, 0, stream>>>(x8, eid, start, deg,
                                                  (unsigned*)aggb, n);
    fused_gemm_mfma<<<gblocks, 256, 0, stream>>>(xb, aggb, fWl1, fWr1, fs1w1, fs1w2,
        bl1, s1b1, s1b2, (uint4v*)ypkbuf, (uint4v*)spkbuf, csum1, csq1, n, ntiles);
    apply_packed_kernel<<<ntiles, 256, 0, stream>>>((const uint4v*)ypkbuf,
        (const uint4v*)spkbuf, csum1, csq1, g1, be1,
        x1b, (unsigned char*)x18, nullptr, 0, invn, n);

    // ---- layer 2 ----
    aggregate_kernel<<<ablocks, 256, 0, stream>>>(x18, eid, start, deg,
                                                  (unsigned*)aggb, n);
    fused_gemm_mfma<<<gblocks, 256, 0, stream>>>(x1b, aggb, fWl2, fWr2, fs2w1, fs2w2,
        bl2, s2b1, s2b2, (uint4v*)ypkbuf, (uint4v*)spkbuf, csum2, csq2, n, ntiles);
    apply_packed_kernel<<<ntiles, 256, 0, stream>>>((const uint4v*)ypkbuf,
        (const uint4v*)spkbuf, csum2, csq2, g2, be2,
        nullptr, nullptr, (float*)d_out, 1, invn, n);
}

// Round 8
// 391.275 us; speedup vs baseline: 1.8662x; 1.8662x over previous
//
#include <hip/hip_runtime.h>

// GraphSAGE round 16: CSR build with ZERO global atomics.
// r15 measured same-address returning global atomics at ~186 ns each
// (serialized at L2 round-trip) — 380 us for direct scatter; r14's 2-phase
// design also paid ~18 us in its per-bucket atomic chain. Replaced with
// 3-pass deterministic radix: count (LDS hist -> hcnt[block][bucket]),
// prefix (per-bucket Hillis-Steele -> gbase, bcur), place (LDS-local
// offsets, same keys layout). bucket_sort unchanged.
// Everything else identical to r14 (391.5 us verified).

#define F   128
#define FH  64
#define EPS 1e-5f
#define CAP 4096            // slots per bucket (avg fill 2046)

typedef __attribute__((ext_vector_type(8))) short short8v;
typedef __attribute__((ext_vector_type(4))) short short4v;
typedef __attribute__((ext_vector_type(4))) float floatx4;
typedef __attribute__((ext_vector_type(2))) float floatx2;
typedef __attribute__((ext_vector_type(4))) unsigned int uint4v;

__device__ inline unsigned short f2bf(float f) {
    unsigned u = __builtin_bit_cast(unsigned, f);
    u += 0x7fff + ((u >> 16) & 1);          // round-to-nearest-even
    return (unsigned short)(u >> 16);
}
__device__ inline float bflo(unsigned u) { return __builtin_bit_cast(float, u << 16); }
__device__ inline float bfhi(unsigned u) { return __builtin_bit_cast(float, u & 0xffff0000u); }

// async global->LDS, 16B per lane; LDS dest wave-uniform base + lane*16,
// global src per-lane (frag-order permutation is applied on the global side)
__device__ inline void gl_lds16(const void* g, void* l) {
    __builtin_amdgcn_global_load_lds(
        (const __attribute__((address_space(1))) void*)g,
        (__attribute__((address_space(3))) void*)l, 16, 0, 0);
}

#define PIN8(v) asm volatile("" : "+v"(v))

// ---------------- x -> bf16 + fp8 ----------------
__global__ __launch_bounds__(256) void conv_dual_kernel(
    const float* __restrict__ x, unsigned short* __restrict__ xb,
    unsigned* __restrict__ x8, int total4)
{
    int t = blockIdx.x * 256 + threadIdx.x;
    if (t >= total4) return;
    float4 v = reinterpret_cast<const float4*>(x)[t];
    short4v p = { (short)f2bf(v.x), (short)f2bf(v.y), (short)f2bf(v.z), (short)f2bf(v.w) };
    *reinterpret_cast<short4v*>(xb + t * 4) = p;
    unsigned p8 = __builtin_amdgcn_cvt_pk_fp8_f32(v.x, v.y, 0, false);
    p8 = __builtin_amdgcn_cvt_pk_fp8_f32(v.z, v.w, p8, true);
    x8[t] = p8;
}

// ---------------- CSR build pass 1: per-(block,bucket) counts ----------------
__global__ __launch_bounds__(1024) void csr_count_kernel(
    const int* __restrict__ dst, int* __restrict__ hcnt, int E, int CHUNK)
{
    __shared__ int hist[1024];
    const int tid = threadIdx.x;
    const int e0 = blockIdx.x * CHUNK;
    const int e1 = min(e0 + CHUNK, E);
    hist[tid] = 0;
    __syncthreads();
    for (int e = e0 + tid; e < e1; e += 1024)
        atomicAdd(&hist[dst[e] >> 7], 1);          // LDS, non-returning
    __syncthreads();
    hcnt[blockIdx.x * 1024 + tid] = hist[tid];     // coalesced, no atomics
}

// ---------------- CSR build pass 2: per-bucket prefix over blocks ----------------
__global__ __launch_bounds__(512) void csr_prefix_kernel(
    const int* __restrict__ hcnt, int* __restrict__ gbase,
    int* __restrict__ bcur, int CB)
{
    __shared__ int v[512];
    const int b = blockIdx.x;      // bucket
    const int t = threadIdx.x;
    int mine = (t < CB) ? hcnt[t * 1024 + b] : 0;
    v[t] = mine;
    __syncthreads();
    for (int o = 1; o < 512; o <<= 1) {
        int a = (t >= o) ? v[t - o] : 0;
        __syncthreads();
        v[t] += a;
        __syncthreads();
    }
    if (t < CB) gbase[t * 1024 + b] = b * CAP + (v[t] - mine);  // exclusive base
    if (t == 0) bcur[b] = v[511];                                // exact total
}

// ---------------- CSR build pass 3: place (LDS-local offsets only) ----------------
__global__ __launch_bounds__(1024) void csr_place_kernel(
    const int* __restrict__ src, const int* __restrict__ dst,
    const int* __restrict__ gbase, int* __restrict__ keys, int E, int CHUNK, int B)
{
    __shared__ int hist[1024];
    __shared__ int lbase[1024];
    const int tid = threadIdx.x;
    const int e0 = blockIdx.x * CHUNK;
    const int e1 = min(e0 + CHUNK, E);
    hist[tid] = 0;
    lbase[tid] = (tid < B) ? gbase[blockIdx.x * 1024 + tid] : 0;
    __syncthreads();
    for (int e = e0 + tid; e < e1; e += 1024) {
        int d = dst[e];
        int b = d >> 7;
        int p = lbase[b] + atomicAdd(&hist[b], 1);  // LDS returning (fast)
        if (p < (b + 1) * CAP)                      // overflow guard
            keys[p] = (src[e] << 7) | (d & 127);
    }
}

__global__ __launch_bounds__(256) void bucket_sort_kernel(
    const int* __restrict__ keys, const int* __restrict__ bcur,
    int* __restrict__ eid, int* __restrict__ start, int* __restrict__ deg, int n)
{
    __shared__ int cnt[128], cur[128], sc[128];
    __shared__ int sorted[CAP];
    const int b = blockIdx.x;
    const int tid = threadIdx.x;
    const int base = b * CAP;
    int count = bcur[b];                 // exact fill
    if (count > CAP) count = CAP;
    const int v0 = b << 7;

    if (tid < 128) cnt[tid] = 0;
    __syncthreads();
    for (int i = tid; i < count; i += 256)
        atomicAdd(&cnt[keys[base + i] & 127], 1);
    __syncthreads();
    if (tid < 128) sc[tid] = cnt[tid];
    __syncthreads();
    for (int o = 1; o < 128; o <<= 1) {
        int a = (tid < 128 && tid >= o) ? sc[tid - o] : 0;
        __syncthreads();
        if (tid < 128) sc[tid] += a;
        __syncthreads();
    }
    if (tid < 128) {
        int excl = sc[tid] - cnt[tid];
        int v = v0 + tid;
        if (v < n) { start[v] = base + excl; deg[v] = cnt[tid]; }
        cur[tid] = excl;
    }
    __syncthreads();
    for (int i = tid; i < count; i += 256) {
        int k = keys[base + i];
        int p = atomicAdd(&cur[k & 127], 1);
        sorted[p] = k >> 7;
    }
    __syncthreads();
    for (int i = tid; i < count; i += 256) eid[base + i] = sorted[i];
}

// ---------------- gather aggregation (fp8 rows): agg[v] = mean x[N(v)] ------------
// v3: 8-edge unroll -> 4 gather loads in flight per lane; floatx2 pk adds.
// lanes 0-31 = even edges, 32-63 = odd edges; lane accumulates feats 4q..4q+3.
__global__ __launch_bounds__(256) void aggregate_kernel(
    const unsigned* __restrict__ x8w, const int* __restrict__ eid,
    const int* __restrict__ start, const int* __restrict__ deg,
    unsigned int* __restrict__ aggb2, int n)
{
    int w = (blockIdx.x * 256 + threadIdx.x) >> 6;
    int l = threadIdx.x & 63;
    if (w >= n) return;
    const int beg  = start[w];
    const int c    = deg[w];
    const int half = l >> 5;
    const int q    = l & 31;
    floatx2 acc01 = {0.f, 0.f};
    floatx2 acc23 = {0.f, 0.f};
    int off = beg, rem = c;
    while (rem > 0) {
        int m = rem < 64 ? rem : 64;
        int id = (l < m) ? eid[off + l] : 0;
        int j = 0;
        for (; j + 7 < m; j += 8) {                 // 8 edges: 4 per half
            int sA = __shfl(id, j + half);
            int sB = __shfl(id, j + 2 + half);
            int sC = __shfl(id, j + 4 + half);
            int sD = __shfl(id, j + 6 + half);
            unsigned dA = x8w[(size_t)sA * 32 + q];
            unsigned dB = x8w[(size_t)sB * 32 + q];
            unsigned dC = x8w[(size_t)sC * 32 + q];
            unsigned dD = x8w[(size_t)sD * 32 + q];
            acc01 += __builtin_amdgcn_cvt_pk_f32_fp8((int)dA, false);
            acc23 += __builtin_amdgcn_cvt_pk_f32_fp8((int)dA, true);
            acc01 += __builtin_amdgcn_cvt_pk_f32_fp8((int)dB, false);
            acc23 += __builtin_amdgcn_cvt_pk_f32_fp8((int)dB, true);
            acc01 += __builtin_amdgcn_cvt_pk_f32_fp8((int)dC, false);
            acc23 += __builtin_amdgcn_cvt_pk_f32_fp8((int)dC, true);
            acc01 += __builtin_amdgcn_cvt_pk_f32_fp8((int)dD, false);
            acc23 += __builtin_amdgcn_cvt_pk_f32_fp8((int)dD, true);
        }
        for (; j + 1 < m; j += 2) {                 // 2 edges: 1 per half
            int sA = __shfl(id, j + half);
            unsigned dA = x8w[(size_t)sA * 32 + q];
            acc01 += __builtin_amdgcn_cvt_pk_f32_fp8((int)dA, false);
            acc23 += __builtin_amdgcn_cvt_pk_f32_fp8((int)dA, true);
        }
        if (j < m) {                                // single leftover edge
            int sA = __shfl(id, j);                 // shfl while converged
            if (half == 0) {
                unsigned dA = x8w[(size_t)sA * 32 + q];
                acc01 += __builtin_amdgcn_cvt_pk_f32_fp8((int)dA, false);
                acc23 += __builtin_amdgcn_cvt_pk_f32_fp8((int)dA, true);
            }
        }
        off += m; rem -= m;
    }
    float a0 = acc01.x, a1 = acc01.y, a2 = acc23.x, a3 = acc23.y;
    a0 += __shfl_xor(a0, 32);
    a1 += __shfl_xor(a1, 32);
    a2 += __shfl_xor(a2, 32);
    a3 += __shfl_xor(a3, 32);
    if (half == 0) {
        float inv = 1.0f / fmaxf((float)c, 1.0f);
        uint2 p;
        p.x = (unsigned)f2bf(a0 * inv) | ((unsigned)f2bf(a1 * inv) << 16);
        p.y = (unsigned)f2bf(a2 * inv) | ((unsigned)f2bf(a3 * inv) << 16);
        *reinterpret_cast<uint2*>(aggb2 + (size_t)w * 64 + 2 * q) = p;
    }
}

// ---------------- weight prep: fp32 [K][N] -> bf16 fragment order ----------------
struct PrepArgs { const float* s[8]; unsigned short* d[8]; };

__global__ __launch_bounds__(256) void prep_all_kernel(PrepArgs a)
{
    int t = blockIdx.x * 256 + threadIdx.x;
    int m, idx, K, N;
    if (t < 4 * 16384)            { m = t >> 14;                 idx = t & 16383; K = 128; N = 128; }
    else if (t < 4 * 16384 + 2 * 8192) { int u = t - 4 * 16384;  m = 4 + (u >> 13); idx = u & 8191; K = 128; N = 64; }
    else                          { int u = t - 4 * 16384 - 2 * 8192; if (u >= 2 * 8192) return;
                                    m = 6 + (u >> 13); idx = u & 8191; K = 64; N = 128; }
    int k = idx / N, c = idx % N;
    int ct = c >> 4, ks = k >> 5;
    int lane = (c & 15) + (((k & 31) >> 3) << 4);
    int j = k & 7;
    a.d[m][((ct * (K >> 5) + ks) * 64 + lane) * 8 + j] = f2bf(a.s[m][idx]);
}

// ---------------- fused MFMA GEMM: pinned weights, async staging, 2 tiles ----------
__global__ __launch_bounds__(256, 3) void fused_gemm_mfma(
    const unsigned short* __restrict__ xb, const unsigned short* __restrict__ aggb,
    const unsigned short* __restrict__ wlf, const unsigned short* __restrict__ wrf,
    const unsigned short* __restrict__ whf, const unsigned short* __restrict__ wsf,
    const float* __restrict__ bl, const float* __restrict__ sb1,
    const float* __restrict__ sb2,
    uint4v* __restrict__ ypk4, uint4v* __restrict__ spk4,
    float* __restrict__ colsum, float* __restrict__ colsq, int n, int ntiles)
{
    __shared__ unsigned short xsf[16 * 64 * 8];   // 16 KB: x frags
    __shared__ unsigned short abuf[16 * 64 * 8];  // 16 KB: agg frags
    __shared__ unsigned short hbuf[64 * 88];      // 11 KB: relu(h)

    const int tid = threadIdx.x;
    const int w = tid >> 6;
    const int l = tid & 63;

    // ---- register-resident B fragments, loaded ONCE, pinned ----
    const short8v* wl8 = (const short8v*)wlf;
    const short8v* wr8 = (const short8v*)wrf;
    const short8v* wh8 = (const short8v*)whf;
    const short8v* ws8 = (const short8v*)wsf;
    short8v bWl[2][4], bWr[2][4];
#pragma unroll
    for (int ct = 0; ct < 2; ++ct)
#pragma unroll
        for (int ks = 0; ks < 4; ++ks) {
            int idx = ((w * 2 + ct) * 4 + ks) * 64 + l;
            bWl[ct][ks] = wl8[idx];
            bWr[ct][ks] = wr8[idx];
        }
    short8v bh[4];
#pragma unroll
    for (int ks = 0; ks < 4; ++ks) bh[ks] = wh8[(w * 4 + ks) * 64 + l];
    short8v bs[2][2];
#pragma unroll
    for (int ct = 0; ct < 2; ++ct)
#pragma unroll
        for (int ks = 0; ks < 2; ++ks)
            bs[ct][ks] = ws8[((w * 2 + ct) * 2 + ks) * 64 + l];
#pragma unroll
    for (int ct = 0; ct < 2; ++ct)
#pragma unroll
        for (int ks = 0; ks < 4; ++ks) { PIN8(bWl[ct][ks]); PIN8(bWr[ct][ks]); }
#pragma unroll
    for (int ks = 0; ks < 4; ++ks) PIN8(bh[ks]);
#pragma unroll
    for (int ct = 0; ct < 2; ++ct)
#pragma unroll
        for (int ks = 0; ks < 2; ++ks) PIN8(bs[ct][ks]);

    const int col0 = w * 32 + (l & 15);
    const float bias0 = bl[col0], bias1 = bl[col0 + 16];
    const int hcol = w * 16 + (l & 15);
    const float hbias = sb1[hcol];
    const float sbias0 = sb2[col0], sbias1 = sb2[col0 + 16];

    const short8v* xs8 = (const short8v*)xsf;
    const short8v* as8 = (const short8v*)abuf;
    const int r15 = l & 15;
    const int s23 = l >> 4;

    float psum0 = 0.f, psq0 = 0.f, psum1 = 0.f, psq1 = 0.f;

    for (int ti = 0; ti < 2; ++ti) {
        const int t = blockIdx.x * 2 + ti;
        if (t >= ntiles) break;
        const int r0 = t * 64;
        const size_t pbase = (size_t)t * 1024;

        // ---- async staging: linear LDS dest, frag-order global permutation ----
#pragma unroll
        for (int c = 0; c < 4; ++c) {
            int u = w * 4 + c;                      // region 0..15
            int rt = u >> 2, ks = u & 3;
            int row = r0 + rt * 16 + r15;
            if (row >= n) row = n - 1;
            size_t goff = (size_t)row * F + (size_t)(ks * 4 + s23) * 8;   // shorts
            gl_lds16(xb + goff,   &xsf[u * 512]);
            gl_lds16(aggb + goff, &abuf[u * 512]);
        }
        __syncthreads();   // staging complete (vmcnt drained)

        // ---- phase Y+H: MFMAs; packed y store + stats; h straight to hbuf ----
#pragma unroll
        for (int rt = 0; rt < 4; ++rt) {
            floatx4 acc0 = {0.f, 0.f, 0.f, 0.f};
            floatx4 acc1 = {0.f, 0.f, 0.f, 0.f};
            floatx4 hacc = {0.f, 0.f, 0.f, 0.f};
#pragma unroll
            for (int ks = 0; ks < 4; ++ks) {
                short8v ax = xs8[(rt * 4 + ks) * 64 + l];
                short8v aa = as8[(rt * 4 + ks) * 64 + l];
                acc0 = __builtin_amdgcn_mfma_f32_16x16x32_bf16(aa, bWl[0][ks], acc0, 0, 0, 0);
                acc0 = __builtin_amdgcn_mfma_f32_16x16x32_bf16(ax, bWr[0][ks], acc0, 0, 0, 0);
                acc1 = __builtin_amdgcn_mfma_f32_16x16x32_bf16(aa, bWl[1][ks], acc1, 0, 0, 0);
                acc1 = __builtin_amdgcn_mfma_f32_16x16x32_bf16(ax, bWr[1][ks], acc1, 0, 0, 0);
                hacc = __builtin_amdgcn_mfma_f32_16x16x32_bf16(ax, bh[ks], hacc, 0, 0, 0);
            }
            int rowb = r0 + rt * 16 + (l >> 4) * 4;
            int hrowb = rt * 16 + (l >> 4) * 4;
            uint4v yq;
#pragma unroll
            for (int reg = 0; reg < 4; ++reg) {
                float v0 = acc0[reg] + bias0;
                float v1 = acc1[reg] + bias1;
                yq[reg] = (unsigned)f2bf(v0) | ((unsigned)f2bf(v1) << 16);
                if (rowb + reg < n) {
                    psum0 += v0; psq0 += v0 * v0;
                    psum1 += v1; psq1 += v1 * v1;
                }
                hbuf[(hrowb + reg) * 88 + hcol] = f2bf(fmaxf(hacc[reg] + hbias, 0.f));
            }
            ypk4[pbase + rt * 256 + tid] = yq;       // 1 KB/wave contiguous
        }
        __syncthreads();   // h visible; all frag reads retired

        // ---- phase S MFMAs (reads hbuf); packed skip store ----
#pragma unroll
        for (int rt = 0; rt < 4; ++rt) {
            floatx4 s0 = {0.f, 0.f, 0.f, 0.f};
            floatx4 s1 = {0.f, 0.f, 0.f, 0.f};
#pragma unroll
            for (int ks = 0; ks < 2; ++ks) {
                short8v ah = *(const short8v*)&hbuf[(rt * 16 + (l & 15)) * 88 + ks * 32 + (l >> 4) * 8];
                s0 = __builtin_amdgcn_mfma_f32_16x16x32_bf16(ah, bs[0][ks], s0, 0, 0, 0);
                s1 = __builtin_amdgcn_mfma_f32_16x16x32_bf16(ah, bs[1][ks], s1, 0, 0, 0);
            }
            uint4v sq;
#pragma unroll
            for (int reg = 0; reg < 4; ++reg)
                sq[reg] = (unsigned)f2bf(s0[reg] + sbias0) |
                          ((unsigned)f2bf(s1[reg] + sbias1) << 16);
            spk4[pbase + rt * 256 + tid] = sq;
        }
        // next tile's staging follows its own barrier -> race-free
    }

    // ---- BN partial stats: one atomic set per block (both tiles) ----
    psum0 += __shfl_xor(psum0, 16); psum0 += __shfl_xor(psum0, 32);
    psq0  += __shfl_xor(psq0, 16);  psq0  += __shfl_xor(psq0, 32);
    psum1 += __shfl_xor(psum1, 16); psum1 += __shfl_xor(psum1, 32);
    psq1  += __shfl_xor(psq1, 16);  psq1  += __shfl_xor(psq1, 32);
    if (l < 16) {
        unsafeAtomicAdd(&colsum[col0], psum0);
        unsafeAtomicAdd(&colsq[col0], psq0);
        unsafeAtomicAdd(&colsum[col0 + 16], psum1);
        unsafeAtomicAdd(&colsq[col0 + 16], psq1);
    }
}

// ---------------- apply: packed reads, inline BN finalize, direct stores ----------
__global__ __launch_bounds__(256) void apply_packed_kernel(
    const uint4v* __restrict__ ypk4, const uint4v* __restrict__ spk4,
    const float* __restrict__ csum, const float* __restrict__ csq,
    const float* __restrict__ g, const float* __restrict__ beta,
    unsigned short* __restrict__ out_bf, unsigned char* __restrict__ out_f8,
    float* __restrict__ out_f32, int out_fp32, float invn, int n)
{
    const int tid = threadIdx.x;
    const int w = tid >> 6, l = tid & 63;
    const int col0 = w * 32 + (l & 15);
    const int r0 = blockIdx.x * 64;
    const size_t pbase = (size_t)blockIdx.x * 1024;

    const float mu0 = csum[col0] * invn;
    const float mu1 = csum[col0 + 16] * invn;
    const float sc0 = rsqrtf(csq[col0] * invn - mu0 * mu0 + EPS) * g[col0];
    const float sc1 = rsqrtf(csq[col0 + 16] * invn - mu1 * mu1 + EPS) * g[col0 + 16];
    const float sh0 = beta[col0] - mu0 * sc0;
    const float sh1 = beta[col0 + 16] - mu1 * sc1;

#pragma unroll
    for (int rt = 0; rt < 4; ++rt) {
        uint4v yv = ypk4[pbase + rt * 256 + tid];
        uint4v sv = spk4[pbase + rt * 256 + tid];
        int rowb = r0 + rt * 16 + (l >> 4) * 4;
#pragma unroll
        for (int reg = 0; reg < 4; ++reg) {
            int row = rowb + reg;
            if (row >= n) continue;
            float o0 = fmaxf(bflo(yv[reg]) * sc0 + sh0 + bflo(sv[reg]), 0.f);
            float o1 = fmaxf(bfhi(yv[reg]) * sc1 + sh1 + bfhi(sv[reg]), 0.f);
            if (out_fp32) {
                out_f32[(size_t)row * F + col0]      = o0;
                out_f32[(size_t)row * F + col0 + 16] = o1;
            } else {
                out_bf[(size_t)row * F + col0]      = f2bf(o0);
                out_bf[(size_t)row * F + col0 + 16] = f2bf(o1);
                unsigned pk = __builtin_amdgcn_cvt_pk_fp8_f32(o0, o1, 0, false);
                out_f8[(size_t)row * F + col0]      = (unsigned char)(pk & 0xff);
                out_f8[(size_t)row * F + col0 + 16] = (unsigned char)((pk >> 8) & 0xff);
            }
        }
    }
}

extern "C" void kernel_launch(void* const* d_in, const int* in_sizes, int n_in,
                              void* d_out, int out_size, void* d_ws, size_t ws_size,
                              hipStream_t stream)
{
    const float* x    = (const float*)d_in[0];
    const int*   ei   = (const int*)d_in[1];
    const float* Wl1  = (const float*)d_in[2];
    const float* bl1  = (const float*)d_in[3];
    const float* Wr1  = (const float*)d_in[4];
    const float* Wl2  = (const float*)d_in[5];
    const float* bl2  = (const float*)d_in[6];
    const float* Wr2  = (const float*)d_in[7];
    const float* s1w1 = (const float*)d_in[8];
    const float* s1b1 = (const float*)d_in[9];
    const float* s1w2 = (const float*)d_in[10];
    const float* s1b2 = (const float*)d_in[11];
    const float* s2w1 = (const float*)d_in[12];
    const float* s2b1 = (const float*)d_in[13];
    const float* s2w2 = (const float*)d_in[14];
    const float* s2b2 = (const float*)d_in[15];
    const float* g1   = (const float*)d_in[16];
    const float* be1  = (const float*)d_in[17];
    const float* g2   = (const float*)d_in[18];
    const float* be2  = (const float*)d_in[19];

    const int n = in_sizes[0] / F;       // 100000
    const int E = in_sizes[1] / 2;       // 1600000
    const int* src = ei;
    const int* dst = ei + E;
    const int B = (n + 127) >> 7;        // 782 buckets
    const int ntiles = (n + 63) >> 6;    // 1563
    const int gblocks = (ntiles + 1) >> 1; // 782, 2 tiles/block

    // CSR chunking: CB blocks of CHUNK edges, CB <= 512 for the prefix kernel
    int CHUNK = 4096;
    int CB = (E + CHUNK - 1) / CHUNK;    // 391 at E=1.6M
    if (CB > 512) {
        CHUNK = ((E + 511) / 512 + 1023) & ~1023;
        CB = (E + CHUNK - 1) / CHUNK;
    }

    // ---- workspace carve-up (float units) ----
    float* ws = (float*)d_ws;
    size_t off = 0;
    float* csum1 = ws + off; off += F;
    float* csq1  = ws + off; off += F;
    float* csum2 = ws + off; off += F;
    float* csq2  = ws + off; off += F;
    int* bcur = (int*)(ws + off); off += 1024;
    unsigned short* xb    = (unsigned short*)(ws + off); off += (size_t)n * F / 2;
    unsigned short* x1b   = (unsigned short*)(ws + off); off += (size_t)n * F / 2;
    unsigned* ypkbuf = (unsigned*)(ws + off); off += (size_t)ntiles * 4096;   // packed y
    unsigned* spkbuf = (unsigned*)(ws + off); off += (size_t)ntiles * 4096;   // packed skip
    unsigned short* aggb  = (unsigned short*)(ws + off); off += (size_t)n * F / 2;
    unsigned* x8  = (unsigned*)(ws + off); off += (size_t)n * F / 4;   // fp8 rows
    unsigned* x18 = (unsigned*)(ws + off); off += (size_t)n * F / 4;
    unsigned short* wbf   = (unsigned short*)(ws + off);
    size_t woff = 0;
    unsigned short* fWl1  = wbf + woff; woff += F * F;
    unsigned short* fWr1  = wbf + woff; woff += F * F;
    unsigned short* fWl2  = wbf + woff; woff += F * F;
    unsigned short* fWr2  = wbf + woff; woff += F * F;
    unsigned short* fs1w1 = wbf + woff; woff += F * FH;
    unsigned short* fs2w1 = wbf + woff; woff += F * FH;
    unsigned short* fs1w2 = wbf + woff; woff += FH * F;
    unsigned short* fs2w2 = wbf + woff; woff += FH * F;
    off += (woff + 1) / 2;
    int* iws = (int*)(ws + off);
    size_t ioff = 0;
    int* start = iws + ioff; ioff += n;
    int* deg   = iws + ioff; ioff += n;
    int* keys  = iws + ioff; ioff += (size_t)B * CAP;
    int* eid   = iws + ioff; ioff += (size_t)B * CAP;
    int* hcnt  = iws + ioff; ioff += (size_t)CB * 1024;
    int* gbase = iws + ioff; ioff += (size_t)CB * 1024;

    const int total4 = n * (F / 4);
    const int ablocks = (n + 3) / 4;
    const float invn = 1.0f / (float)n;

    // ---- single startup memset: stats (2 KB) + bcur (4 KB) ----
    hipMemsetAsync(ws, 0, 512 * sizeof(float) + 1024 * sizeof(int), stream);

    // ---- x -> bf16 + fp8 ----
    conv_dual_kernel<<<(total4 + 255) / 256, 256, 0, stream>>>(x, xb, x8, total4);

    // ---- CSR build: count -> prefix -> place (no global atomics) ----
    csr_count_kernel<<<CB, 1024, 0, stream>>>(dst, hcnt, E, CHUNK);
    csr_prefix_kernel<<<B, 512, 0, stream>>>(hcnt, gbase, bcur, CB);
    csr_place_kernel<<<CB, 1024, 0, stream>>>(src, dst, gbase, keys, E, CHUNK, B);
    bucket_sort_kernel<<<B, 256, 0, stream>>>(keys, bcur, eid, start, deg, n);

    // ---- weight prep ----
    PrepArgs pa;
    pa.s[0] = Wl1;  pa.d[0] = fWl1;
    pa.s[1] = Wr1;  pa.d[1] = fWr1;
    pa.s[2] = Wl2;  pa.d[2] = fWl2;
    pa.s[3] = Wr2;  pa.d[3] = fWr2;
    pa.s[4] = s1w1; pa.d[4] = fs1w1;
    pa.s[5] = s2w1; pa.d[5] = fs2w1;
    pa.s[6] = s1w2; pa.d[6] = fs1w2;
    pa.s[7] = s2w2; pa.d[7] = fs2w2;
    prep_all_kernel<<<384, 256, 0, stream>>>(pa);

    // ---- layer 1 ----
    aggregate_kernel<<<ablocks, 256, 0, stream>>>(x8, eid, start, deg,
                                                  (unsigned*)aggb, n);
    fused_gemm_mfma<<<gblocks, 256, 0, stream>>>(xb, aggb, fWl1, fWr1, fs1w1, fs1w2,
        bl1, s1b1, s1b2, (uint4v*)ypkbuf, (uint4v*)spkbuf, csum1, csq1, n, ntiles);
    apply_packed_kernel<<<ntiles, 256, 0, stream>>>((const uint4v*)ypkbuf,
        (const uint4v*)spkbuf, csum1, csq1, g1, be1,
        x1b, (unsigned char*)x18, nullptr, 0, invn, n);

    // ---- layer 2 ----
    aggregate_kernel<<<ablocks, 256, 0, stream>>>(x18, eid, start, deg,
                                                  (unsigned*)aggb, n);
    fused_gemm_mfma<<<gblocks, 256, 0, stream>>>(x1b, aggb, fWl2, fWr2, fs2w1, fs2w2,
        bl2, s2b1, s2b2, (uint4v*)ypkbuf, (uint4v*)spkbuf, csum2, csq2, n, ntiles);
    apply_packed_kernel<<<ntiles, 256, 0, stream>>>((const uint4v*)ypkbuf,
        (const uint4v*)spkbuf, csum2, csq2, g2, be2,
        nullptr, nullptr, (float*)d_out, 1, invn, n);
}